// Round 10
// baseline (198.630 us; speedup 1.0000x reference)
//
#include <hip/hip_runtime.h>

// Problem constants (B=64, C=512, H=W=32 -> HW=1024)
#define B_    64
#define C_    512
#define HW_   1024
#define S_    32                 // hw positions per slab
#define NSLAB (HW_ / S_)         // 32 slabs per batch
#define TPB   512                // 8 waves

// ---------------------------------------------------------------------------
// Kernel 1: register-resident slab {conv + softmax stats + weighted pooling}.
// grid = B*NSLAB = 2048 blocks, 512 thr. Thread t holds hw-quad j = t&7
// (4 hw values) for the 8 channels {i*64 + (t>>3)} as float4 v[8]; w values
// go straight to registers (no LDS staging barrier). l is read from HBM
// exactly once, into registers, used twice (c-phase + U-phase).
// Only 2 barriers: {c-partials,gw} -> stats, stats -> U-phase.
// ---------------------------------------------------------------------------
__global__ __launch_bounds__(TPB) void k1_slab(
        const float* __restrict__ l,
        const float* __restrict__ g,
        const float* __restrict__ w,
        float* __restrict__ c_out,
        float* __restrict__ U,
        float2* __restrict__ stats) {
    __shared__ float redc[8 * 8 * 4];    // [wave][j] float4 c-partials (1 KB)
    __shared__ float redg[8];            // gw wave partials
    __shared__ float e_lds[S_];

    const int blk  = blockIdx.x;
    const int b    = blk >> 5;           // / NSLAB
    const int slab = blk & (NSLAB - 1);
    const int t    = threadIdx.x;
    const int lane = t & 63;
    const int wid  = t >> 6;             // 8 waves
    const int j    = t & 7;              // hw-quad index (hw = 4j..4j+3)
    const int co   = t >> 3;             // channel offset 0..63

    // --- 1. issue all global loads first: 8x l-float4, 8x w, g, w[t] ---
    const float4* l4 = reinterpret_cast<const float4*>(l);
    float4 v[8];
    #pragma unroll
    for (int i = 0; i < 8; ++i)
        v[i] = l4[((size_t)b * C_ + (i * 64 + co)) * (HW_ / 4)
                  + slab * (S_ / 4) + j];
    float wr[8];
    #pragma unroll
    for (int i = 0; i < 8; ++i) wr[i] = w[i * 64 + co];  // L2-hot broadcast

    // --- 2. gw partial (in the load shadow) ---
    float p = g[b * C_ + t] * w[t];
    #pragma unroll
    for (int off = 32; off > 0; off >>= 1) p += __shfl_xor(p, off);
    if (lane == 0) redg[wid] = p;

    // --- 3. c partials: 8 channels x this thread's 4 hw ---
    float4 cp = {0.f, 0.f, 0.f, 0.f};
    #pragma unroll
    for (int i = 0; i < 8; ++i) {
        cp.x = fmaf(v[i].x, wr[i], cp.x);
        cp.y = fmaf(v[i].y, wr[i], cp.y);
        cp.z = fmaf(v[i].z, wr[i], cp.z);
        cp.w = fmaf(v[i].w, wr[i], cp.w);
    }
    // reduce over lane bits 3,4,5 (all lanes sharing this j in the wave)
    #pragma unroll
    for (int m = 8; m <= 32; m <<= 1) {
        cp.x += __shfl_xor(cp.x, m);
        cp.y += __shfl_xor(cp.y, m);
        cp.z += __shfl_xor(cp.z, m);
        cp.w += __shfl_xor(cp.w, m);
    }
    if (lane < 8)                          // lane == j here
        reinterpret_cast<float4*>(redc)[wid * 8 + lane] = cp;
    __syncthreads();

    // --- 4. stats: lanes 0-31 finalize c (hw = t), softmax stats ---
    if (t < S_) {
        float c = 0.f;
        #pragma unroll
        for (int wv = 0; wv < 8; ++wv) c += redc[wv * 32 + t];
        float gw = 0.f;
        #pragma unroll
        for (int i = 0; i < 8; ++i) gw += redg[i];
        c += gw;
        c_out[(size_t)b * HW_ + slab * S_ + t] = c;

        float m = c;
        #pragma unroll
        for (int off = 16; off > 0; off >>= 1) m = fmaxf(m, __shfl_xor(m, off));
        const float e = __expf(c - m);
        float E = e;
        #pragma unroll
        for (int off = 16; off > 0; off >>= 1) E += __shfl_xor(E, off);
        e_lds[t] = e;
        if (t == 0) stats[b * NSLAB + slab] = make_float2(m, E);
    }
    __syncthreads();

    // --- 5. U phase: reuse v[] registers; e4 broadcast per j-group ---
    const float4 e4 = reinterpret_cast<const float4*>(e_lds)[j];
    float u[8];
    #pragma unroll
    for (int i = 0; i < 8; ++i)
        u[i] = v[i].x * e4.x + v[i].y * e4.y + v[i].z * e4.z + v[i].w * e4.w;
    // reduce over lane bits 0,1,2 (the 8 lanes sharing channel i*64+co)
    #pragma unroll
    for (int i = 0; i < 8; ++i) {
        u[i] += __shfl_xor(u[i], 1);
        u[i] += __shfl_xor(u[i], 2);
        u[i] += __shfl_xor(u[i], 4);
    }
    // lane picks the channel whose i equals its j (static-index select) ...
    float uval = u[0];
    #pragma unroll
    for (int i = 1; i < 8; ++i) if (j == i) uval = u[i];
    // ... then transpose-lane so stores are 32-B contiguous runs:
    // lane l receives ch = (l>>3)*64 + wid*8 + (l&7)
    uval = __shfl(uval, ((lane & 7) << 3) | (lane >> 3));
    const int ch = (lane >> 3) * 64 + wid * 8 + (lane & 7);
    U[((size_t)b * NSLAB + slab) * C_ + ch] = uval;
}

// ---------------------------------------------------------------------------
// Kernel 2: combine slabs. grid = B*8 = 512 blocks, 256 thr = 4 waves.
// Block (b, cg) handles 64 channels; each wave sums 8 slabs; LDS reduce.
// U loads issued FIRST; stats computed in their shadow.
// g_out[b,ch] = sum_s U_s[ch] * e^{m_s - m} / Z.
// ---------------------------------------------------------------------------
__global__ __launch_bounds__(256) void k2_finish(
        const float* __restrict__ U,
        const float2* __restrict__ stats,
        float* __restrict__ gout) {
    __shared__ float scale_lds[NSLAB];
    __shared__ float invZ_lds;
    __shared__ float part2[4 * 64];

    const int blk = blockIdx.x;
    const int b   = blk >> 3;
    const int cg  = blk & 7;
    const int t   = threadIdx.x;
    const int wid = t >> 6;
    const int cl  = t & 63;
    const int ch  = cg * 64 + cl;

    // --- issue the 8 U loads first (independent, deep in flight) ---
    float uv[8];
    #pragma unroll
    for (int si = 0; si < 8; ++si)
        uv[si] = U[((size_t)b * NSLAB + wid * 8 + si) * C_ + ch];

    // --- stats in the load shadow (lanes 0-31 of wave 0) ---
    if (t < NSLAB) {
        const float2 me = stats[b * NSLAB + t];
        float m = me.x;
        #pragma unroll
        for (int off = 16; off > 0; off >>= 1) m = fmaxf(m, __shfl_xor(m, off));
        const float sc = __expf(me.x - m);
        float Z = me.y * sc;
        #pragma unroll
        for (int off = 16; off > 0; off >>= 1) Z += __shfl_xor(Z, off);
        scale_lds[t] = sc;
        if (t == 0) invZ_lds = __frcp_rn(Z);
    }
    __syncthreads();

    float acc = 0.f;
    #pragma unroll
    for (int si = 0; si < 8; ++si)
        acc = fmaf(uv[si], scale_lds[wid * 8 + si], acc);
    part2[wid * 64 + cl] = acc;
    __syncthreads();

    if (wid == 0) {
        float r = part2[cl] + part2[64 + cl] + part2[128 + cl] + part2[192 + cl];
        gout[(size_t)b * C_ + ch] = r * invZ_lds;
    }
}

// ---------------------------------------------------------------------------
extern "C" void kernel_launch(void* const* d_in, const int* in_sizes, int n_in,
                              void* d_out, int out_size, void* d_ws, size_t ws_size,
                              hipStream_t stream) {
    const float* l = (const float*)d_in[0];   // [B, C, H, W]
    const float* g = (const float*)d_in[1];   // [B, C]
    const float* w = (const float*)d_in[2];   // [C]
    float*  c_out = (float*)d_out;                      // c: B*HW floats
    float*  gout  = (float*)d_out + (size_t)B_ * HW_;   // g_out: B*C floats
    float*  U     = (float*)d_ws;                       // B*NSLAB*C = 4 MiB
    float2* stats = (float2*)(U + (size_t)B_ * NSLAB * C_);  // B*NSLAB float2

    k1_slab<<<B_ * NSLAB, TPB, 0, stream>>>(l, g, w, c_out, U, stats);
    k2_finish<<<B_ * 8, 256, 0, stream>>>(U, stats, gout);
}